// Round 1
// baseline (957.209 us; speedup 1.0000x reference)
//
#include <hip/hip_runtime.h>

#define C 64

// ---------------------------------------------------------------------------
// Kernel 1: per-node dot product d[i] = dot(x[i,:], lin_w)
// One 64-lane wave per node: coalesced 256B row read, shuffle reduce.
// ---------------------------------------------------------------------------
__global__ void dot_kernel(const float* __restrict__ x,
                           const float* __restrict__ w,
                           float* __restrict__ d, int n) {
    int gtid = blockIdx.x * blockDim.x + threadIdx.x;
    int node = gtid >> 6;          // wave index == node
    int lane = threadIdx.x & 63;
    if (node >= n) return;
    float v = x[(size_t)node * C + lane] * w[lane];
    // wave-64 butterfly-free down reduce
    v += __shfl_down(v, 32, 64);
    v += __shfl_down(v, 16, 64);
    v += __shfl_down(v, 8, 64);
    v += __shfl_down(v, 4, 64);
    v += __shfl_down(v, 2, 64);
    v += __shfl_down(v, 1, 64);
    if (lane == 0) d[node] = v;
}

// ---------------------------------------------------------------------------
// Kernel 2: learned[i] = lin_b  (self-loop message contributes exactly lin_b)
// ---------------------------------------------------------------------------
__global__ void init_learned_kernel(float* __restrict__ learned,
                                    const float* __restrict__ lin_b, int n) {
    int i = blockIdx.x * blockDim.x + threadIdx.x;
    if (i < n) learned[i] = lin_b[0];
}

// ---------------------------------------------------------------------------
// Kernel 3: per-edge scalar scatter:
//   learned[dst] += d[src] - d[dst] + lin_b      (only needed for dst >= FIRST)
// ---------------------------------------------------------------------------
__global__ void edge_learned_kernel(const int* __restrict__ ei,
                                    const float* __restrict__ d,
                                    const float* __restrict__ lin_b,
                                    float* __restrict__ learned,
                                    int n, int first) {
    int e = blockIdx.x * blockDim.x + threadIdx.x;
    if (e >= n) return;
    int t = ei[n + e];           // dst
    if (t < first) return;      // learned only consumed for nodes >= FIRST
    int s = ei[e];               // src
    atomicAdd(&learned[t], d[s] - d[t] + lin_b[0]);
}

// ---------------------------------------------------------------------------
// Kernel 4: per-edge row scatter. One wave per edge:
//   score = base(e) + (e>=FIRST ? learned[e] : 0)   [score indexed by EDGE pos]
//   out[dst,:] += x[src,:] * score                   (fp32 atomics)
// ---------------------------------------------------------------------------
__global__ void scatter_kernel(const float* __restrict__ x,
                               const int* __restrict__ ei,
                               const float* __restrict__ learned,
                               const float* __restrict__ w1,
                               const float* __restrict__ w2,
                               const float* __restrict__ w3,
                               float* __restrict__ out,
                               int n, int first) {
    int gtid = blockIdx.x * blockDim.x + threadIdx.x;
    int e = gtid >> 6;           // wave index == edge
    int lane = threadIdx.x & 63;
    if (e >= n) return;
    float score;
    if (e < first) {
        score = w1[0];
    } else {
        float base = (((e - first) & 1) == 0) ? w2[0] : w3[0];
        score = base + learned[e];
    }
    int s = ei[e];
    int t = ei[n + e];
    float v = x[(size_t)s * C + lane] * score;
    atomicAdd(&out[(size_t)t * C + lane], v);
}

// ---------------------------------------------------------------------------
// Kernel 5: in-place ReLU, float4-vectorized (out_size = N*64, divisible by 4)
// ---------------------------------------------------------------------------
__global__ void relu_kernel(float4* __restrict__ out, size_t n4) {
    size_t i = (size_t)blockIdx.x * blockDim.x + threadIdx.x;
    if (i >= n4) return;
    float4 v = out[i];
    v.x = fmaxf(v.x, 0.0f);
    v.y = fmaxf(v.y, 0.0f);
    v.z = fmaxf(v.z, 0.0f);
    v.w = fmaxf(v.w, 0.0f);
    out[i] = v;
}

extern "C" void kernel_launch(void* const* d_in, const int* in_sizes, int n_in,
                              void* d_out, int out_size, void* d_ws, size_t ws_size,
                              hipStream_t stream) {
    const float* x     = (const float*)d_in[0];   // [N, 64]
    const float* lin_w = (const float*)d_in[1];   // [1, 64]
    const float* lin_b = (const float*)d_in[2];   // [1]
    const float* w1    = (const float*)d_in[3];   // [1]
    const float* w2    = (const float*)d_in[4];   // [1]
    const float* w3    = (const float*)d_in[5];   // [1]
    const int*   ei    = (const int*)d_in[6];     // [2, N] (row0=src, row1=dst)
    float* out = (float*)d_out;                   // [N, 64]

    const int n = in_sizes[0] / C;                // num nodes == num edges
    const int first = n / 3;                      // FIRST

    float* d_dot   = (float*)d_ws;                // [n]
    float* learned = d_dot + n;                   // [n]

    // out accumulates via atomics -> must start at zero (harness poisons 0xAA)
    hipMemsetAsync(d_out, 0, (size_t)out_size * sizeof(float), stream);

    // 1. per-node dot products (wave per node, 4 nodes per 256-thread block)
    {
        dim3 grid((n + 3) / 4), block(256);
        dot_kernel<<<grid, block, 0, stream>>>(x, lin_w, d_dot, n);
    }
    // 2. learned[i] = lin_b
    {
        dim3 grid((n + 255) / 256), block(256);
        init_learned_kernel<<<grid, block, 0, stream>>>(learned, lin_b, n);
    }
    // 3. per-edge scalar atomics into learned
    {
        dim3 grid((n + 255) / 256), block(256);
        edge_learned_kernel<<<grid, block, 0, stream>>>(ei, d_dot, lin_b, learned,
                                                        n, first);
    }
    // 4. per-edge row gather/scale/atomic-scatter (wave per edge)
    {
        dim3 grid((n + 3) / 4), block(256);
        scatter_kernel<<<grid, block, 0, stream>>>(x, ei, learned, w1, w2, w3,
                                                   out, n, first);
    }
    // 5. ReLU in place
    {
        size_t n4 = (size_t)out_size / 4;
        dim3 grid((unsigned)((n4 + 255) / 256)), block(256);
        relu_kernel<<<grid, block, 0, stream>>>((float4*)out, n4);
    }
}

// Round 2
// 924.746 us; speedup vs baseline: 1.0351x; 1.0351x over previous
//
#include <hip/hip_runtime.h>

#define C 64

// ---------------------------------------------------------------------------
// K1: per-node dot product d[i] = dot(x[i,:], lin_w). Wave per node.
// ---------------------------------------------------------------------------
__global__ void dot_kernel(const float* __restrict__ x,
                           const float* __restrict__ w,
                           float* __restrict__ d, int n) {
    int gtid = blockIdx.x * blockDim.x + threadIdx.x;
    int node = gtid >> 6;
    int lane = threadIdx.x & 63;
    if (node >= n) return;
    float v = x[(size_t)node * C + lane] * w[lane];
    v += __shfl_down(v, 32, 64);
    v += __shfl_down(v, 16, 64);
    v += __shfl_down(v, 8, 64);
    v += __shfl_down(v, 4, 64);
    v += __shfl_down(v, 2, 64);
    v += __shfl_down(v, 1, 64);
    if (lane == 0) d[node] = v;
}

// ---------------------------------------------------------------------------
// K2: learned[i] = lin_b (self-loop message x[i]-x[i]=0 contributes lin_b)
// ---------------------------------------------------------------------------
__global__ void init_learned_kernel(float* __restrict__ learned,
                                    const float* __restrict__ lin_b, int n) {
    int i = blockIdx.x * blockDim.x + threadIdx.x;
    if (i < n) learned[i] = lin_b[0];
}

// ---------------------------------------------------------------------------
// K3: fused histogram + learned scatter.
//   count[dst] += 1                                  (for CSR build)
//   learned[dst] += d[src]-d[dst]+lin_b  (only consumed for dst >= FIRST)
// ---------------------------------------------------------------------------
__global__ void hist_learned_kernel(const int* __restrict__ ei,
                                    const float* __restrict__ d,
                                    const float* __restrict__ lin_b,
                                    float* __restrict__ learned,
                                    int* __restrict__ count,
                                    int n, int first) {
    int e = blockIdx.x * blockDim.x + threadIdx.x;
    if (e >= n) return;
    int t = ei[n + e];
    atomicAdd(&count[t], 1);
    if (t >= first) {
        int s = ei[e];
        atomicAdd(&learned[t], d[s] - d[t] + lin_b[0]);
    }
}

// ---------------------------------------------------------------------------
// Exclusive scan of count[] -> off[] (3 kernels). n = numBlocks*256 exactly.
// ---------------------------------------------------------------------------
__global__ void scan1_kernel(const int* __restrict__ count,
                             int* __restrict__ off,
                             int* __restrict__ partial) {
    __shared__ int sh[256];
    int tid = threadIdx.x;
    int gid = blockIdx.x * 256 + tid;
    int v = count[gid];
    sh[tid] = v;
    __syncthreads();
    for (int o = 1; o < 256; o <<= 1) {
        int t = (tid >= o) ? sh[tid - o] : 0;
        __syncthreads();
        sh[tid] += t;
        __syncthreads();
    }
    off[gid] = sh[tid] - v;                 // block-local exclusive
    if (tid == 255) partial[blockIdx.x] = sh[255];
}

__global__ void scan2_kernel(int* __restrict__ partial, int nb) {
    // single block of 256 threads; each thread owns nb/256 contiguous partials
    __shared__ int sh[256];
    int tid = threadIdx.x;
    int chunk = nb / 256;
    int base = tid * chunk;
    int sum = 0;
    for (int k = 0; k < chunk; ++k) sum += partial[base + k];
    sh[tid] = sum;
    __syncthreads();
    for (int o = 1; o < 256; o <<= 1) {
        int t = (tid >= o) ? sh[tid - o] : 0;
        __syncthreads();
        sh[tid] += t;
        __syncthreads();
    }
    int running = sh[tid] - sum;            // exclusive prefix of this chunk
    for (int k = 0; k < chunk; ++k) {
        int v = partial[base + k];
        partial[base + k] = running;
        running += v;
    }
}

__global__ void scan3_kernel(int* __restrict__ off,
                             const int* __restrict__ partial) {
    int gid = blockIdx.x * 256 + threadIdx.x;
    off[gid] += partial[blockIdx.x];
}

// ---------------------------------------------------------------------------
// K4: reorder edges into CSR buckets, baking the per-edge score.
//   score[e] = base(e) + (e>=FIRST ? learned[e] : 0)  [indexed by EDGE pos]
// ---------------------------------------------------------------------------
__global__ void reorder_kernel(const int* __restrict__ ei,
                               const float* __restrict__ learned,
                               const int* __restrict__ off,
                               int* __restrict__ cursor,
                               int2* __restrict__ srcscore,
                               const float* __restrict__ w1,
                               const float* __restrict__ w2,
                               const float* __restrict__ w3,
                               int n, int first) {
    int e = blockIdx.x * blockDim.x + threadIdx.x;
    if (e >= n) return;
    float score;
    if (e < first) {
        score = w1[0];
    } else {
        float base = (((e - first) & 1) == 0) ? w2[0] : w3[0];
        score = base + learned[e];          // coalesced read of learned
    }
    int s = ei[e];
    int t = ei[n + e];
    int pos = off[t] + atomicAdd(&cursor[t], 1);
    srcscore[pos] = make_int2(s, __float_as_int(score));
}

// ---------------------------------------------------------------------------
// K5: gather. One wave per node: out[i,:] = relu(sum_j x[src_j,:]*score_j).
// No atomics, out written exactly once, ReLU fused.
// ---------------------------------------------------------------------------
__global__ void gather_kernel(const float* __restrict__ x,
                              const int* __restrict__ off,
                              const int2* __restrict__ srcscore,
                              float* __restrict__ out, int n) {
    int gtid = blockIdx.x * blockDim.x + threadIdx.x;
    int node = gtid >> 6;
    int lane = threadIdx.x & 63;
    if (node >= n) return;
    int beg = off[node];
    int end = (node + 1 < n) ? off[node + 1] : n;
    float acc = 0.0f;
    for (int j = beg; j < end; ++j) {
        int2 p = srcscore[j];               // wave-uniform 8B load
        acc += x[(size_t)p.x * C + lane] * __int_as_float(p.y);
    }
    out[(size_t)node * C + lane] = fmaxf(acc, 0.0f);
}

extern "C" void kernel_launch(void* const* d_in, const int* in_sizes, int n_in,
                              void* d_out, int out_size, void* d_ws, size_t ws_size,
                              hipStream_t stream) {
    const float* x     = (const float*)d_in[0];   // [N, 64]
    const float* lin_w = (const float*)d_in[1];   // [1, 64]
    const float* lin_b = (const float*)d_in[2];   // [1]
    const float* w1    = (const float*)d_in[3];
    const float* w2    = (const float*)d_in[4];
    const float* w3    = (const float*)d_in[5];
    const int*   ei    = (const int*)d_in[6];     // [2, N]
    float* out = (float*)d_out;                   // [N, 64]

    const int n = in_sizes[0] / C;                // nodes == edges (1048576)
    const int first = n / 3;

    // workspace layout (28 MB + 16 KB)
    float* d_dot   = (float*)d_ws;                // n
    float* learned = d_dot + n;                   // n
    int*   count   = (int*)(learned + n);         // n
    int*   off     = count + n;                   // n
    int*   cursor  = off + n;                     // n
    int2*  srcscore = (int2*)(cursor + n);        // n int2
    int*   partial = (int*)(srcscore + n);        // n/256

    const int nb = n / 256;                       // scan blocks (4096)

    hipMemsetAsync(count, 0, (size_t)n * sizeof(int), stream);
    hipMemsetAsync(cursor, 0, (size_t)n * sizeof(int), stream);

    dot_kernel<<<dim3((n + 3) / 4), dim3(256), 0, stream>>>(x, lin_w, d_dot, n);
    init_learned_kernel<<<dim3(nb), dim3(256), 0, stream>>>(learned, lin_b, n);
    hist_learned_kernel<<<dim3(nb), dim3(256), 0, stream>>>(ei, d_dot, lin_b,
                                                            learned, count, n, first);
    scan1_kernel<<<dim3(nb), dim3(256), 0, stream>>>(count, off, partial);
    scan2_kernel<<<dim3(1), dim3(256), 0, stream>>>(partial, nb);
    scan3_kernel<<<dim3(nb), dim3(256), 0, stream>>>(off, partial);
    reorder_kernel<<<dim3(nb), dim3(256), 0, stream>>>(ei, learned, off, cursor,
                                                       srcscore, w1, w2, w3, n, first);
    gather_kernel<<<dim3((n + 3) / 4), dim3(256), 0, stream>>>(x, off, srcscore,
                                                               out, n);
}

// Round 3
// 672.458 us; speedup vs baseline: 1.4234x; 1.3752x over previous
//
#include <hip/hip_runtime.h>

#define C 64

// ---------------------------------------------------------------------------
// K1: per-node dot d[i] = dot(x[i,:], lin_w), plus learned[i] = lin_b init.
// Four nodes per wave: 16 lanes/node, float4 each (16 lanes * 16B = 256B row).
// Wave reads 1024B contiguous. Reduce via 4 xor-shuffles within 16-lane group.
// ---------------------------------------------------------------------------
__global__ void dot_kernel(const float4* __restrict__ x4,
                           const float4* __restrict__ w4,
                           const float* __restrict__ lin_b,
                           float* __restrict__ d,
                           float* __restrict__ learned, int n) {
    int gtid = blockIdx.x * blockDim.x + threadIdx.x;
    int wave = gtid >> 6;
    int lane = threadIdx.x & 63;
    int sub  = lane >> 4;          // which node within the wave (0..3)
    int sl   = lane & 15;          // lane within node group
    int node = wave * 4 + sub;
    if (node >= n) return;
    float4 v = x4[(size_t)node * 16 + sl];
    float4 w = w4[sl];
    float t = v.x * w.x + v.y * w.y + v.z * w.z + v.w * w.w;
    t += __shfl_xor(t, 8, 64);
    t += __shfl_xor(t, 4, 64);
    t += __shfl_xor(t, 2, 64);
    t += __shfl_xor(t, 1, 64);
    if (sl == 0) {
        d[node] = t;
        learned[node] = lin_b[0];  // self-loop message contributes exactly lin_b
    }
}

// ---------------------------------------------------------------------------
// K2: histogram + rank capture + learned scatter.
//   rank[e]   = order of edge e among edges sharing dst  (from atomic return)
//   count[t] += 1
//   learned[t] += d[s]-d[t]+lin_b          (only consumed for t >= FIRST)
// ---------------------------------------------------------------------------
__global__ void hist_kernel(const int* __restrict__ ei,
                            const float* __restrict__ d,
                            const float* __restrict__ lin_b,
                            float* __restrict__ learned,
                            int* __restrict__ count,
                            int* __restrict__ rank,
                            int n, int first) {
    int e = blockIdx.x * blockDim.x + threadIdx.x;
    if (e >= n) return;
    int t = ei[n + e];
    rank[e] = atomicAdd(&count[t], 1);
    if (t >= first) {
        int s = ei[e];
        atomicAdd(&learned[t], d[s] - d[t] + lin_b[0]);
    }
}

// ---------------------------------------------------------------------------
// Exclusive scan of count[] -> off[] (3 kernels). n = nb*256 exactly.
// ---------------------------------------------------------------------------
__global__ void scan1_kernel(const int* __restrict__ count,
                             int* __restrict__ off,
                             int* __restrict__ partial) {
    __shared__ int sh[256];
    int tid = threadIdx.x;
    int gid = blockIdx.x * 256 + tid;
    int v = count[gid];
    sh[tid] = v;
    __syncthreads();
    for (int o = 1; o < 256; o <<= 1) {
        int t = (tid >= o) ? sh[tid - o] : 0;
        __syncthreads();
        sh[tid] += t;
        __syncthreads();
    }
    off[gid] = sh[tid] - v;
    if (tid == 255) partial[blockIdx.x] = sh[255];
}

__global__ void scan2_kernel(int* __restrict__ partial, int nb) {
    __shared__ int sh[256];
    int tid = threadIdx.x;
    int chunk = nb / 256;
    int base = tid * chunk;
    int sum = 0;
    for (int k = 0; k < chunk; ++k) sum += partial[base + k];
    sh[tid] = sum;
    __syncthreads();
    for (int o = 1; o < 256; o <<= 1) {
        int t = (tid >= o) ? sh[tid - o] : 0;
        __syncthreads();
        sh[tid] += t;
        __syncthreads();
    }
    int running = sh[tid] - sum;
    for (int k = 0; k < chunk; ++k) {
        int v = partial[base + k];
        partial[base + k] = running;
        running += v;
    }
}

__global__ void scan3_kernel(int* __restrict__ off,
                             const int* __restrict__ partial) {
    int gid = blockIdx.x * 256 + threadIdx.x;
    off[gid] += partial[blockIdx.x];
}

// ---------------------------------------------------------------------------
// K3: reorder edges into CSR buckets (atomic-free; uses captured rank).
//   score[e] = base(e) + (e>=FIRST ? learned[e] : 0)   [indexed by EDGE pos]
// ---------------------------------------------------------------------------
__global__ void reorder_kernel(const int* __restrict__ ei,
                               const float* __restrict__ learned,
                               const int* __restrict__ off,
                               const int* __restrict__ rank,
                               int2* __restrict__ srcscore,
                               const float* __restrict__ w1,
                               const float* __restrict__ w2,
                               const float* __restrict__ w3,
                               int n, int first) {
    int e = blockIdx.x * blockDim.x + threadIdx.x;
    if (e >= n) return;
    float score;
    if (e < first) {
        score = w1[0];
    } else {
        float base = (((e - first) & 1) == 0) ? w2[0] : w3[0];
        score = base + learned[e];
    }
    int s = ei[e];
    int t = ei[n + e];
    int pos = off[t] + rank[e];
    srcscore[pos] = make_int2(s, __float_as_int(score));
}

// ---------------------------------------------------------------------------
// K4: gather. Four nodes per wave (16 lanes x float4 per node):
//   out[i,:] = relu(sum_j x[src_j,:]*score_j)
// 4 independent load chains per wave -> 4x latency overlap vs wave-per-node.
// ---------------------------------------------------------------------------
__global__ void gather_kernel(const float4* __restrict__ x4,
                              const int* __restrict__ off,
                              const int2* __restrict__ srcscore,
                              float4* __restrict__ out4, int n) {
    int gtid = blockIdx.x * blockDim.x + threadIdx.x;
    int wave = gtid >> 6;
    int lane = threadIdx.x & 63;
    int sub  = lane >> 4;
    int sl   = lane & 15;
    int node = wave * 4 + sub;
    if (node >= n) return;
    int beg = off[node];
    int end = (node + 1 < n) ? off[node + 1] : n;
    float4 acc = make_float4(0.f, 0.f, 0.f, 0.f);
    for (int j = beg; j < end; ++j) {
        int2 p = srcscore[j];
        float s = __int_as_float(p.y);
        float4 v = x4[(size_t)p.x * 16 + sl];
        acc.x += v.x * s;
        acc.y += v.y * s;
        acc.z += v.z * s;
        acc.w += v.w * s;
    }
    acc.x = fmaxf(acc.x, 0.f);
    acc.y = fmaxf(acc.y, 0.f);
    acc.z = fmaxf(acc.z, 0.f);
    acc.w = fmaxf(acc.w, 0.f);
    out4[(size_t)node * 16 + sl] = acc;
}

extern "C" void kernel_launch(void* const* d_in, const int* in_sizes, int n_in,
                              void* d_out, int out_size, void* d_ws, size_t ws_size,
                              hipStream_t stream) {
    const float* x     = (const float*)d_in[0];   // [N, 64]
    const float* lin_w = (const float*)d_in[1];   // [1, 64]
    const float* lin_b = (const float*)d_in[2];   // [1]
    const float* w1    = (const float*)d_in[3];
    const float* w2    = (const float*)d_in[4];
    const float* w3    = (const float*)d_in[5];
    const int*   ei    = (const int*)d_in[6];     // [2, N]
    float* out = (float*)d_out;                   // [N, 64]

    const int n = in_sizes[0] / C;                // nodes == edges (1048576)
    const int first = n / 3;
    const int nb = n / 256;                       // 4096

    // workspace: 7n ints/floats + nb
    float* d_dot    = (float*)d_ws;               // n
    float* learned  = d_dot + n;                  // n
    int*   count    = (int*)(learned + n);        // n
    int*   off      = count + n;                  // n
    int*   rank     = off + n;                    // n
    int2*  srcscore = (int2*)(rank + n);          // n int2
    int*   partial  = (int*)(srcscore + n);       // nb

    hipMemsetAsync(count, 0, (size_t)n * sizeof(int), stream);

    // wave serves 4 nodes -> n/4 waves -> n*16 threads total -> n/16 blocks
    dot_kernel<<<dim3(n / 16), dim3(256), 0, stream>>>(
        (const float4*)x, (const float4*)lin_w, lin_b, d_dot, learned, n);
    hist_kernel<<<dim3(nb), dim3(256), 0, stream>>>(ei, d_dot, lin_b, learned,
                                                    count, rank, n, first);
    scan1_kernel<<<dim3(nb), dim3(256), 0, stream>>>(count, off, partial);
    scan2_kernel<<<dim3(1), dim3(256), 0, stream>>>(partial, nb);
    scan3_kernel<<<dim3(nb), dim3(256), 0, stream>>>(off, partial);
    reorder_kernel<<<dim3(nb), dim3(256), 0, stream>>>(ei, learned, off, rank,
                                                       srcscore, w1, w2, w3, n, first);
    gather_kernel<<<dim3(n / 16), dim3(256), 0, stream>>>(
        (const float4*)x, off, srcscore, (float4*)out, n);
}